// Round 8
// baseline (275.751 us; speedup 1.0000x reference)
//
#include <hip/hip_runtime.h>
#include <stdint.h>

// C=32 captions, I=32 images, T=40 words, R=36 regions, D=1024.
// R19: revert gates2_k to the R17 structure (115us measured; R18's ct-16 +
// single-barrier restructure regressed to 143) and fix the remaining
// address-scatter: cwT operand loads were 16x64B segments per wave (lane
// stride 128B). New PRE-FRAGMENTED layout cwF[i][db][ks][lane][8] = exact
// MFMA A-frag order -> each wave operand load is ONE contiguous 1KB segment;
// gemmw's elementwise cwT stores compact 2KB-spread -> 256B/quad. Plus a
// one-chunk-ahead register prefetch of cwF frags inside R17's unchanged
// 2-barrier skeleton (hides under epilogue VALU; structure untouched).
// prep_k/score_k unchanged; gemms_k only changes the cwT store indexing.

typedef unsigned short u16;
typedef __attribute__((ext_vector_type(8))) short bf16x8;
typedef __attribute__((ext_vector_type(4))) float f32x4;

#define MFMA_BF16(a, b, c) __builtin_amdgcn_mfma_f32_16x16x32_bf16((a), (b), (c), 0, 0, 0)

__device__ __forceinline__ float bf2f(u16 u) {
  union { unsigned v; float f; } x; x.v = ((unsigned)u) << 16; return x.f;
}
__device__ __forceinline__ u16 f2bf(float f) {  // round-to-nearest-even
  union { float f; unsigned v; } x; x.f = f;
  return (u16)((x.v + 0x7fffu + ((x.v >> 16) & 1u)) >> 16);
}
__device__ __forceinline__ float frcp(float x) { return __builtin_amdgcn_rcpf(x); }
// async 16B global->LDS (DMA; LDS dest = wave-uniform base + lane*16)
__device__ __forceinline__ void gl2lds16(const u16* g, u16* l) {
  __builtin_amdgcn_global_load_lds((const __attribute__((address_space(1))) void*)g,
                                   (__attribute__((address_space(3))) void*)l, 16, 0, 0);
}

// ---------------------------------------------------------------------------
// prep: [0,2432) fp32->bf16 cvt; [2432,6528) W transpose; [6528,6848) capnorm;
// [6848,8896) zero cwF region (pads; gemms fills r<36 slots afterwards).
__global__ void prep_k(const float* __restrict__ img, const float* __restrict__ cap,
                       const float* __restrict__ Wl, const float* __restrict__ Wg,
                       u16* __restrict__ imgb, u16* __restrict__ capb,
                       u16* __restrict__ WTl, u16* __restrict__ WTg,
                       float* __restrict__ cnorm, u16* __restrict__ cwF0) {
  __shared__ u16 tile[32][33];
  const int b = blockIdx.x, tid = threadIdx.x;
  if (b < 2432) {
    const float* src; u16* dst; int idx;
    if (b < 1152) { src = img; dst = imgb; idx = (b * 256 + tid) * 4; }
    else { src = cap; dst = capb; idx = ((b - 1152) * 256 + tid) * 4; }
    const float4 v = *(const float4*)(src + idx);
    u16 o[4] = {f2bf(v.x), f2bf(v.y), f2bf(v.z), f2bf(v.w)};
    *(uint2*)(dst + idx) = *(const uint2*)o;
  } else if (b < 6528) {
    const int b2 = b - 2432;
    const int bx = b2 & 63, by = (b2 >> 6) & 31, bz = b2 >> 11;
    const float* src = bz ? Wg : Wl;
    u16* dst = bz ? WTg : WTl;
    const int k0 = bx * 32, n0 = by * 32;
    const int tx = tid & 31, ty = tid >> 5;
#pragma unroll
    for (int j = 0; j < 4; ++j)
      tile[ty + 8 * j][tx] = f2bf(src[(size_t)(k0 + ty + 8 * j) * 1024 + n0 + tx]);
    __syncthreads();
#pragma unroll
    for (int j = 0; j < 4; ++j)
      dst[(size_t)(n0 + ty + 8 * j) * 2048 + k0 + tx] = tile[tx][ty + 8 * j];
  } else if (b < 6848) {
    const int wv = tid >> 6, lane = tid & 63;
    const int row = (b - 6528) * 4 + wv;  // < 1280
    const float* p = cap + ((size_t)row << 10) + lane * 16;
    float s = 0.f;
#pragma unroll
    for (int e = 0; e < 16; ++e) { float v = p[e]; s += v * v; }
#pragma unroll
    for (int off = 32; off > 0; off >>= 1) s += __shfl_down(s, off, 64);
    if (lane == 0) cnorm[row] = sqrtf(s);
  } else {
    const int idx = ((b - 6848) * 256 + tid) * 8;
    uint4 z; z.x = z.y = z.z = z.w = 0u;
    *(uint4*)(cwF0 + idx) = z;
  }
}

// ---------------------------------------------------------------------------
// Merged GEMM launch: [0,640) s1gemm; [640,944) gemmw; [944,976) gram.
// gemmw's img part writes cwF fragment layout:
//   element (i, d, r): db=d>>4, lane=((r&31)>>3)*16+(d&15), ks=r>>5, e=r&7
//   index = ((((i*64+db)*2+ks)*64+lane)*8+e
__global__ __launch_bounds__(256, 2) void gemms_k(
    const u16* __restrict__ capb, const u16* __restrict__ imgb,
    const u16* __restrict__ WTl, const u16* __restrict__ WTg,
    u16* __restrict__ preL, u16* __restrict__ preG,
    u16* __restrict__ cwFL, u16* __restrict__ cwFG,
    const float* __restrict__ bL, const float* __restrict__ bG,
    float* __restrict__ S1, u16* __restrict__ Ghi, u16* __restrict__ Glo) {
  __shared__ __align__(16) char lsU[20480];
  const int bid = blockIdx.x;
  const int tid = threadIdx.x;
  const int wv = tid >> 6, lane = tid & 63;
  const int quad = lane >> 4, l15 = lane & 15;
  const bf16x8 zero8 = {0, 0, 0, 0, 0, 0, 0, 0};

  if (bid < 640) {
    // ---- S1 GEMM: out[i][m][r] = sum_d cap[m,d]*ctx_i[r,d]; m-tile 64.
    u16* lsA = (u16*)lsU;
    u16* lsB = (u16*)(lsU + 4096);
    const int i = bid & 31, m0 = (bid >> 5) * 64;
    const u16* B = imgb + (size_t)i * 36 * 1024;
    f32x4 acc[3];
#pragma unroll
    for (int b = 0; b < 3; ++b) acc[b] = (f32x4){0.f, 0.f, 0.f, 0.f};
    for (int kt = 0; kt < 32; ++kt) {
      if (kt) __syncthreads();
      const int rr = tid >> 2, j = tid & 3;
      const int js = j ^ ((rr >> 2) & 3);
      gl2lds16(capb + (size_t)(m0 + rr) * 1024 + kt * 32 + js * 8,
               lsA + (size_t)(wv * 64) * 8);
      const int rc = rr < 36 ? rr : 35;
      gl2lds16(B + (size_t)rc * 1024 + kt * 32 + js * 8,
               lsB + (size_t)(wv * 64) * 8);
      __syncthreads();
      const int ra = wv * 16 + l15;
      const bf16x8 a2 = *(const bf16x8*)(lsA + ra * 32 + (quad ^ ((ra >> 2) & 3)) * 8);
      bf16x8 b3[3];
#pragma unroll
      for (int nf = 0; nf < 3; ++nf) {
        const int rb = nf * 16 + l15;
        const bf16x8 bv = *(const bf16x8*)(lsB + rb * 32 + (quad ^ ((rb >> 2) & 3)) * 8);
        b3[nf] = (rb < 36) ? bv : zero8;
      }
#pragma unroll
      for (int nf = 0; nf < 3; ++nf) acc[nf] = MFMA_BF16(a2, b3[nf], acc[nf]);
    }
#pragma unroll
    for (int nf = 0; nf < 3; ++nf)
#pragma unroll
      for (int rg = 0; rg < 4; ++rg) {
        const int m = m0 + wv * 16 + quad * 4 + rg;
        S1[((size_t)i * 1280 + m) * 48 + nf * 16 + l15] = acc[nf][rg];
      }
  } else if (bid < 944) {
    // ---- dual-B GEMM over A = [capb(1280); imgb(1152)], K=1024.
    u16* lsA = (u16*)lsU;
    u16* lsBl = (u16*)(lsU + 4096);
    u16* lsBg = (u16*)(lsU + 12288);
    const int b2 = bid - 640;
    const int bm = b2 >> 3, bn = b2 & 7;
    const bool iscap = bm < 20;
    const u16* A = iscap ? capb + (size_t)bm * 64 * 1024
                         : imgb + (size_t)(bm - 20) * 64 * 1024;
    const int kofs = iscap ? 0 : 1024;
    const int wm = (wv & 1) * 32, wn = (wv >> 1) * 64;
    f32x4 accL[2][4], accG[2][4];
#pragma unroll
    for (int a = 0; a < 2; ++a)
#pragma unroll
      for (int b = 0; b < 4; ++b) {
        accL[a][b] = (f32x4){0.f, 0.f, 0.f, 0.f};
        accG[a][b] = (f32x4){0.f, 0.f, 0.f, 0.f};
      }
    for (int kt = 0; kt < 32; ++kt) {
      if (kt) __syncthreads();
      {
        const int row = tid >> 2, c8 = tid & 3;
        const int js = c8 ^ (row & 3);
        gl2lds16(A + (size_t)row * 1024 + kt * 32 + js * 8,
                 lsA + (size_t)(wv * 64) * 8);
      }
#pragma unroll
      for (int s = 0; s < 2; ++s) {
        const int idx = s * 256 + tid;
        const int row = idx >> 2, c8 = idx & 3;
        const int js = c8 ^ (row & 3);
        const size_t bro = (size_t)(bn * 128 + row) * 2048 + kofs + kt * 32 + js * 8;
        gl2lds16(WTl + bro, lsBl + (size_t)(s * 256 + wv * 64) * 8);
        gl2lds16(WTg + bro, lsBg + (size_t)(s * 256 + wv * 64) * 8);
      }
      __syncthreads();
      bf16x8 af[2], bl8[4], bg8[4];
#pragma unroll
      for (int mt = 0; mt < 2; ++mt) {
        const int ra = wm + mt * 16 + l15;
        af[mt] = *(const bf16x8*)(lsA + ra * 32 + (quad ^ (ra & 3)) * 8);
      }
#pragma unroll
      for (int nt = 0; nt < 4; ++nt) {
        const int rb = wn + nt * 16 + l15;
        const int off = rb * 32 + (quad ^ (rb & 3)) * 8;
        bl8[nt] = *(const bf16x8*)(lsBl + off);
        bg8[nt] = *(const bf16x8*)(lsBg + off);
      }
#pragma unroll
      for (int mt = 0; mt < 2; ++mt)
#pragma unroll
        for (int nt = 0; nt < 4; ++nt) {
          accL[mt][nt] = MFMA_BF16(af[mt], bl8[nt], accL[mt][nt]);
          accG[mt][nt] = MFMA_BF16(af[mt], bg8[nt], accG[mt][nt]);
        }
    }
#pragma unroll
    for (int mt = 0; mt < 2; ++mt)
#pragma unroll
      for (int nt = 0; nt < 4; ++nt) {
        const int n = bn * 128 + wn + nt * 16 + l15;
        if (iscap) {
          const float blv = bL[n], bgv = bG[n];
#pragma unroll
          for (int r = 0; r < 4; ++r) {
            const int m = bm * 64 + wm + mt * 16 + quad * 4 + r;
            preL[((size_t)m << 10) + n] = f2bf(accL[mt][nt][r] + blv);
            preG[((size_t)m << 10) + n] = f2bf(accG[mt][nt][r] + bgv);
          }
        } else {
          const int db = n >> 4, l15d = n & 15;
#pragma unroll
          for (int r = 0; r < 4; ++r) {
            const int mi = (bm - 20) * 64 + wm + mt * 16 + quad * 4 + r;
            const int i = (mi * 3641) >> 17;   // floor(mi/36), mi<1152
            const int r36 = mi - i * 36;
            const int ksr = r36 >> 5, qd = (r36 & 31) >> 3, e = r36 & 7;
            const size_t gb =
                ((((size_t)i * 64 + db) * 2 + ksr) * 64 + qd * 16 + l15d) * 8 + e;
            cwFL[gb] = f2bf(accL[mt][nt][r]);
            cwFG[gb] = f2bf(accG[mt][nt][r]);
          }
        }
      }
  } else {
    // ---- per-image Gram: G[i] = ctx_i @ ctx_i^T, [48][64] bf16 hi+lo.
    float* lsS = (float*)lsU;  // 48*52*4 = 9984B
    const int i = bid - 944;
    for (int k = tid; k < 48 * 52; k += 256) lsS[k] = 0.f;
    const u16* arow[3]; bool avalid[3];
#pragma unroll
    for (int mt = 0; mt < 3; ++mt) {
      const int r = mt * 16 + l15;
      avalid[mt] = r < 36;
      arow[mt] = imgb + ((size_t)(i * 36 + (r < 36 ? r : 35)) << 10);
    }
    f32x4 acc[3][3];
#pragma unroll
    for (int a = 0; a < 3; ++a)
#pragma unroll
      for (int b = 0; b < 3; ++b) acc[a][b] = (f32x4){0.f, 0.f, 0.f, 0.f};
    for (int kk = wv * 8; kk < wv * 8 + 8; ++kk) {
      const int ko = kk * 32 + quad * 8;
      bf16x8 af[3];
#pragma unroll
      for (int mt = 0; mt < 3; ++mt)
        af[mt] = avalid[mt] ? *(const bf16x8*)(arow[mt] + ko) : zero8;
#pragma unroll
      for (int mt = 0; mt < 3; ++mt)
#pragma unroll
        for (int nt = 0; nt < 3; ++nt)
          acc[mt][nt] = MFMA_BF16(af[mt], af[nt], acc[mt][nt]);
    }
    __syncthreads();
#pragma unroll
    for (int mt = 0; mt < 3; ++mt)
#pragma unroll
      for (int nt = 0; nt < 3; ++nt)
#pragma unroll
        for (int rg = 0; rg < 4; ++rg)
          atomicAdd(&lsS[(nt * 16 + l15) * 52 + mt * 16 + quad * 4 + rg],
                    acc[mt][nt][rg]);
    __syncthreads();
    if (wv == 0) {
#pragma unroll
      for (int nt = 0; nt < 3; ++nt) {
        const int rp = nt * 16 + l15;
#pragma unroll
        for (int mt = 0; mt < 3; ++mt) {
          const f32x4 g = *(const f32x4*)&lsS[rp * 52 + mt * 16 + quad * 4];
          u16 hv[4], lv[4];
#pragma unroll
          for (int rg = 0; rg < 4; ++rg) {
            hv[rg] = f2bf(g[rg]);
            lv[rg] = f2bf(g[rg] - bf2f(hv[rg]));
          }
          const size_t gb = ((size_t)i * 48 + rp) * 64 + mt * 16 + quad * 4;
          *(uint2*)(Ghi + gb) = *(const uint2*)hv;
          *(uint2*)(Glo + gb) = *(const uint2*)lv;
        }
      }
    }
    for (int k = tid; k < 48 * 16; k += 256) {  // zero cols 48..63
      const size_t gb = ((size_t)i * 48 + (k >> 4)) * 64 + 48 + (k & 15);
      Ghi[gb] = 0; Glo[gb] = 0;
    }
  }
}

// ---------------------------------------------------------------------------
// Fused gate + S2 (R17 structure: 32-ct tile, 2 barriers/chunk, grid 1280).
// cwF fragment loads = single contiguous 1KB/wave; register-prefetched one
// chunk ahead (latency hides under epilogue); pre/capb chunks DMA-staged.
__global__ __launch_bounds__(256, 4) void gates2_k(
    const u16* __restrict__ cwFL, const u16* __restrict__ cwFG,
    const u16* __restrict__ P1, const u16* __restrict__ preL,
    const u16* __restrict__ preG, const u16* __restrict__ capb,
    const u16* __restrict__ imgb, float* __restrict__ S2) {
  __shared__ __align__(16) u16 lsPre[3][32 * 128];  // [buf][ct][128d] swz
  __shared__ __align__(16) float lsS2f[32 * 52];
  const int tid = threadIdx.x;
  const int bid = blockIdx.x;
  const int i = bid & 31, ctt = bid >> 5;  // i fastest: image i -> XCD i%8
  const int ct0 = ctt * 32;
  const int wv = tid >> 6, lane = tid & 63;
  const int quad = lane >> 4, l15 = lane & 15;

  for (int k = tid; k < 32 * 52; k += 256) lsS2f[k] = 0.f;

  // hoisted P1 B-frags (loop-invariant; r>=36 exact zero from score_k)
  bf16x8 bp[2][2];
#pragma unroll
  for (int nt = 0; nt < 2; ++nt)
#pragma unroll
    for (int ks = 0; ks < 2; ++ks)
      bp[nt][ks] = *(const bf16x8*)(
          P1 + ((size_t)i * 1280 + ct0 + nt * 16 + l15) * 64 + ks * 32 + quad * 8);

  const u16* arow[3]; bool avalid[3];
#pragma unroll
  for (int mt = 0; mt < 3; ++mt) {
    const int r = mt * 16 + l15;
    avalid[mt] = r < 36;
    arow[mt] = imgb + ((size_t)(i * 36 + (r < 36 ? r : 35)) << 10);
  }
  const bf16x8 zero8 = {0, 0, 0, 0, 0, 0, 0, 0};

  f32x4 acc2[3][2];
#pragma unroll
  for (int a = 0; a < 3; ++a)
#pragma unroll
    for (int b = 0; b < 2; ++b) acc2[a][b] = (f32x4){0.f, 0.f, 0.f, 0.f};

#define STAGE(dcx)                                                          \
  {                                                                         \
    _Pragma("unroll")                                                       \
    for (int s = 0; s < 2; ++s) {                                           \
      const int idx = s * 256 + tid;                                        \
      const int rr = idx >> 4, j = idx & 15;                                \
      const int js = j ^ (rr & 7);                                          \
      const size_t src = (size_t)(ct0 + rr) * 1024 + (dcx) * 128 + js * 8;  \
      const size_t dst = (size_t)(s * 256 + wv * 64) * 8;                   \
      gl2lds16(preL + src, lsPre[0] + dst);                                 \
      gl2lds16(preG + src, lsPre[1] + dst);                                 \
      gl2lds16(capb + src, lsPre[2] + dst);                                 \
    }                                                                       \
  }

  // cwF fragment register prefetch (one chunk ahead); wave wv owns d rows
  // [wv*32, wv*32+32) of each 128-d chunk -> db = dc*8 + wv*2 + mt.
  bf16x8 cwl[2][2], cwg[2][2];
#define LOADCW(dcx)                                                         \
  {                                                                         \
    _Pragma("unroll")                                                       \
    for (int mt = 0; mt < 2; ++mt)                                          \
      _Pragma("unroll")                                                     \
      for (int ks = 0; ks < 2; ++ks) {                                      \
        const int db = (dcx) * 8 + wv * 2 + mt;                             \
        const size_t co = ((((size_t)i * 64 + db) * 2 + ks) * 64 + lane) * 8; \
        cwl[mt][ks] = *(const bf16x8*)(cwFL + co);                          \
        cwg[mt][ks] = *(const bf16x8*)(cwFG + co);                          \
      }                                                                     \
  }

  STAGE(0);
  LOADCW(0);
  for (int dc = 0; dc < 8; ++dc) {
    __syncthreads();  // staging + prefetch drained; prev epilogue reads fenced

    // ---- gate GEMM from prefetched frags: 32 d (wave) x 32 ct, K=64
    f32x4 accL[2][2], accG[2][2];
#pragma unroll
    for (int a = 0; a < 2; ++a)
#pragma unroll
      for (int b = 0; b < 2; ++b) {
        accL[a][b] = (f32x4){0.f, 0.f, 0.f, 0.f};
        accG[a][b] = (f32x4){0.f, 0.f, 0.f, 0.f};
      }
#pragma unroll
    for (int mt = 0; mt < 2; ++mt)
#pragma unroll
      for (int ks = 0; ks < 2; ++ks)
#pragma unroll
        for (int nt = 0; nt < 2; ++nt) {
          accL[mt][nt] = MFMA_BF16(cwl[mt][ks], bp[nt][ks], accL[mt][nt]);
          accG[mt][nt] = MFMA_BF16(cwg[mt][ks], bp[nt][ks], accG[mt][nt]);
        }
    if (dc < 7) LOADCW(dc + 1);  // 1KB contiguous; hides under epilogue

    // ---- gating epilogue (staged-LDS reads only)
    uint2 ovv[2][2];
#pragma unroll
    for (int mt = 0; mt < 2; ++mt) {
      const int drel = wv * 32 + mt * 16 + quad * 4;
      const int j = drel >> 3;
#pragma unroll
      for (int nt = 0; nt < 2; ++nt) {
        const int rr = nt * 16 + l15;
        const int off = rr * 128 + (j ^ (rr & 7)) * 8 + (quad & 1) * 4;
        const uint2 plv = *(const uint2*)(lsPre[0] + off);
        const uint2 pgv = *(const uint2*)(lsPre[1] + off);
        const uint2 cfv = *(const uint2*)(lsPre[2] + off);
        const float pl4[4] = {bf2f((u16)(plv.x & 0xffffu)), bf2f((u16)(plv.x >> 16)),
                              bf2f((u16)(plv.y & 0xffffu)), bf2f((u16)(plv.y >> 16))};
        const float pg4[4] = {bf2f((u16)(pgv.x & 0xffffu)), bf2f((u16)(pgv.x >> 16)),
                              bf2f((u16)(pgv.y & 0xffffu)), bf2f((u16)(pgv.y >> 16))};
        const float cf4[4] = {bf2f((u16)(cfv.x & 0xffffu)), bf2f((u16)(cfv.x >> 16)),
                              bf2f((u16)(cfv.y & 0xffffu)), bf2f((u16)(cfv.y >> 16))};
        u16 ov[4];
#pragma unroll
        for (int rg = 0; rg < 4; ++rg) {
          const float aL = accL[mt][nt][rg] + pl4[rg];
          const float aG = accG[mt][nt][rg] + pg4[rg];
          const float g = frcp(1.f + __expf(-aG));
          const float u = 2.f * frcp(1.f + __expf(-2.f * aL)) - 1.f;  // tanh
          ov[rg] = f2bf(cf4[rg] * g + u * (1.f - g));
        }
        ovv[mt][nt] = *(const uint2*)ov;
      }
    }
    __syncthreads();  // all lsPre reads done -> next DMA safe
    if (dc < 7) STAGE(dc + 1);  // prefetch under S2 compute

    // ---- S2 partial: B-frag via quad-permute shuffles; wave's 32-d slice
#pragma unroll
    for (int nt = 0; nt < 2; ++nt) {
      unsigned w[4];
#pragma unroll
      for (int j2 = 0; j2 < 4; ++j2) {
        const int srcl = ((quad & 1) * 2 + (j2 >> 1)) * 16 + l15;
        const unsigned a0 =
            __shfl((j2 & 1) ? ovv[0][nt].y : ovv[0][nt].x, srcl, 64);
        const unsigned a1 =
            __shfl((j2 & 1) ? ovv[1][nt].y : ovv[1][nt].x, srcl, 64);
        w[j2] = (quad >= 2) ? a1 : a0;
      }
      union { unsigned u[4]; bf16x8 v; } bq;
      bq.u[0] = w[0]; bq.u[1] = w[1]; bq.u[2] = w[2]; bq.u[3] = w[3];
      const int dg = dc * 128 + wv * 32 + quad * 8;
#pragma unroll
      for (int mt = 0; mt < 3; ++mt) {
        const bf16x8 af = avalid[mt] ? *(const bf16x8*)(arow[mt] + dg) : zero8;
        acc2[mt][nt] = MFMA_BF16(af, bq.v, acc2[mt][nt]);
      }
    }
  }
#undef STAGE
#undef LOADCW
  // ---- merge wave partials (d-slices), write S2 tile
#pragma unroll
  for (int mt = 0; mt < 3; ++mt)
#pragma unroll
    for (int nt = 0; nt < 2; ++nt)
#pragma unroll
      for (int rg = 0; rg < 4; ++rg)
        atomicAdd(&lsS2f[(nt * 16 + l15) * 52 + mt * 16 + quad * 4 + rg],
                  acc2[mt][nt][rg]);
  __syncthreads();
  for (int idx = tid; idx < 384; idx += 256) {
    const int ct = idx / 12, rq = idx % 12;
    *(f32x4*)(S2 + ((size_t)i * 1280 + ct0 + ct) * 48 + rq * 4) =
        *(const f32x4*)&lsS2f[ct * 52 + rq * 4];
  }
}

// ---------------------------------------------------------------------------
// Per-pair scoring (4 pairs/block, one per wave). Softmax(Ssm) -> P;
// pn = sum P*S1; pw = P^T G P; sim = mean cosine. PASS2=0 also writes P1+sim1;
// PASS2=1 writes score = sim1 + sim2.
template <int PASS2>
__global__ __launch_bounds__(256, 2) void score_k(
    const float* __restrict__ Ssm, const float* __restrict__ S1,
    const u16* __restrict__ Ghi, const u16* __restrict__ Glo,
    const float* __restrict__ cnorm, u16* __restrict__ P1,
    float* __restrict__ sim1, float* __restrict__ score) {
  __shared__ __align__(16) u16 lsP[4][48 * 72];
  const int tid = threadIdx.x;
  const int wv = tid >> 6, lane = tid & 63;
  const int quad = lane >> 4, l15 = lane & 15;
  const int pair = blockIdx.x * 4 + wv;
  const int c = pair >> 5, i = pair & 31;
  u16* lsPw = lsP[wv];
  for (int k = lane; k < 1728; k += 64) ((unsigned*)lsPw)[k] = 0u;

  float sS[3][3][4], s1f[3][3][4];
  const float* Sb = Ssm + ((size_t)i * 1280 + c * 40) * 48;
  const float* S1b = S1 + ((size_t)i * 1280 + c * 40) * 48;
#pragma unroll
  for (int nt = 0; nt < 3; ++nt) {
    const int t = nt * 16 + l15;
    const int tr = t < 40 ? t : 39;
#pragma unroll
    for (int mt = 0; mt < 3; ++mt) {
      f32x4 v = *(const f32x4*)(Sb + (size_t)tr * 48 + mt * 16 + quad * 4);
      if (t >= 40) v = (f32x4){0.f, 0.f, 0.f, 0.f};  // keep l2norm-over-t exact
#pragma unroll
      for (int rg = 0; rg < 4; ++rg) sS[mt][nt][rg] = v[rg];
      if (PASS2) {
        const f32x4 w = *(const f32x4*)(S1b + (size_t)tr * 48 + mt * 16 + quad * 4);
#pragma unroll
        for (int rg = 0; rg < 4; ++rg) s1f[mt][nt][rg] = w[rg];
      } else {
#pragma unroll
        for (int rg = 0; rg < 4; ++rg) s1f[mt][nt][rg] = v[rg];
      }
    }
  }

  // ---- leaky + l2norm over t, temperature softmax over r (in-register)
  float rn[3][4];
#pragma unroll
  for (int mt = 0; mt < 3; ++mt)
#pragma unroll
    for (int rg = 0; rg < 4; ++rg) {
      float s2 = 0.f;
#pragma unroll
      for (int nt = 0; nt < 3; ++nt) {
        float v = sS[mt][nt][rg]; v = v > 0.f ? v : 0.1f * v; s2 += v * v;
      }
      s2 += __shfl_xor(s2, 1, 64); s2 += __shfl_xor(s2, 2, 64);
      s2 += __shfl_xor(s2, 4, 64); s2 += __shfl_xor(s2, 8, 64);
      rn[mt][rg] = sqrtf(s2) + 1e-8f;
    }
  float mx[3] = {-3.0e38f, -3.0e38f, -3.0e38f};
#pragma unroll
  for (int mt = 0; mt < 3; ++mt)
#pragma unroll
    for (int nt = 0; nt < 3; ++nt)
#pragma unroll
      for (int rg = 0; rg < 4; ++rg) {
        const int r = mt * 16 + quad * 4 + rg;
        float v = sS[mt][nt][rg]; v = v > 0.f ? v : 0.1f * v;
        float zz = 9.f * v / rn[mt][rg];
        zz = (r < 36) ? zz : -3.0e38f;
        sS[mt][nt][rg] = zz;
        mx[nt] = fmaxf(mx[nt], zz);
      }
#pragma unroll
  for (int nt = 0; nt < 3; ++nt) {
    mx[nt] = fmaxf(mx[nt], __shfl_xor(mx[nt], 16, 64));
    mx[nt] = fmaxf(mx[nt], __shfl_xor(mx[nt], 32, 64));
  }
  float ss[3] = {0.f, 0.f, 0.f};
#pragma unroll
  for (int mt = 0; mt < 3; ++mt)
#pragma unroll
    for (int nt = 0; nt < 3; ++nt)
#pragma unroll
      for (int rg = 0; rg < 4; ++rg) {
        const float e = __expf(sS[mt][nt][rg] - mx[nt]);
        sS[mt][nt][rg] = e; ss[nt] += e;
      }
#pragma unroll
  for (int nt = 0; nt < 3; ++nt) {
    ss[nt] += __shfl_xor(ss[nt], 16, 64);
    ss[nt] += __shfl_xor(ss[nt], 32, 64);
    ss[nt] = 1.f / ss[nt];
  }
#pragma unroll
  for (int nt = 0; nt < 3; ++nt) {
    const int t = nt * 16 + l15;
#pragma unroll
    for (int mt = 0; mt < 3; ++mt) {
#pragma unroll
      for (int rg = 0; rg < 4; ++rg) sS[mt][nt][rg] *= ss[nt];
      if (t < 40) {
        u16 pv[4];
#pragma unroll
        for (int rg = 0; rg < 4; ++rg) pv[rg] = f2bf(sS[mt][nt][rg]);
        *(uint2*)(lsPw + t * 72 + mt * 16 + quad * 4) = *(const uint2*)pv;
      }
    }
  }

  // ---- pn = sum_r P * S1raw (per t)
  float pnv[3] = {0.f, 0.f, 0.f};
#pragma unroll
  for (int nt = 0; nt < 3; ++nt)
#pragma unroll
    for (int mt = 0; mt < 3; ++mt)
#pragma unroll
      for (int rg = 0; rg < 4; ++rg) pnv[nt] += sS[mt][nt][rg] * s1f[mt][nt][rg];

  // ---- P1 global write (GEMM operand layout, stride 64, zeros beyond r=36)
  if (!PASS2) {
    for (int idx = lane; idx < 320; idx += 64) {
      const int t = idx >> 3, j = idx & 7;
      *(uint4*)(P1 + ((size_t)i * 1280 + c * 40 + t) * 64 + j * 8) =
          *(const uint4*)(lsPw + t * 72 + j * 8);
    }
  }

  // ---- pw = P^T G P via Gram MFMA
  bf16x8 afA[3][2];
#pragma unroll
  for (int mtT = 0; mtT < 3; ++mtT)
#pragma unroll
    for (int ks = 0; ks < 2; ++ks)
      afA[mtT][ks] =
          *(const bf16x8*)(lsPw + (mtT * 16 + l15) * 72 + ks * 32 + quad * 8);
  f32x4 gp[3][3];
#pragma unroll
  for (int a = 0; a < 3; ++a)
#pragma unroll
    for (int b = 0; b < 3; ++b) gp[a][b] = (f32x4){0.f, 0.f, 0.f, 0.f};
#pragma unroll
  for (int ks = 0; ks < 2; ++ks)
#pragma unroll
    for (int mtG = 0; mtG < 3; ++mtG) {
      const size_t gb = ((size_t)i * 48 + mtG * 16 + l15) * 64 + ks * 32 + quad * 8;
      const bf16x8 gh = *(const bf16x8*)(Ghi + gb);
      const bf16x8 gl = *(const bf16x8*)(Glo + gb);
#pragma unroll
      for (int mtT = 0; mtT < 3; ++mtT) {
        gp[mtG][mtT] = MFMA_BF16(gh, afA[mtT][ks], gp[mtG][mtT]);
        gp[mtG][mtT] = MFMA_BF16(gl, afA[mtT][ks], gp[mtG][mtT]);
      }
    }
  float pwv[3] = {0.f, 0.f, 0.f};
#pragma unroll
  for (int nt = 0; nt < 3; ++nt)
#pragma unroll
    for (int mt = 0; mt < 3; ++mt)
#pragma unroll
      for (int rg = 0; rg < 4; ++rg)
        pwv[nt] += sS[mt][nt][rg] * gp[mt][nt][rg];
#pragma unroll
  for (int nt = 0; nt < 3; ++nt) {
    pnv[nt] += __shfl_xor(pnv[nt], 16, 64); pnv[nt] += __shfl_xor(pnv[nt], 32, 64);
    pwv[nt] += __shfl_xor(pwv[nt], 16, 64); pwv[nt] += __shfl_xor(pwv[nt], 32, 64);
  }
  float tot = 0.f;
#pragma unroll
  for (int nt = 0; nt < 3; ++nt) {
    const int t = nt * 16 + l15;
    if (t < 40) {
      const float w2 = sqrtf(fmaxf(pwv[nt], 0.f));
      tot += pnv[nt] / fmaxf(cnorm[c * 40 + t] * w2, 1e-8f);
    }
  }
  tot += __shfl_xor(tot, 1, 64); tot += __shfl_xor(tot, 2, 64);
  tot += __shfl_xor(tot, 4, 64); tot += __shfl_xor(tot, 8, 64);
  if (lane == 0) {
    const float s = tot * (1.f / 40.f);
    if (PASS2) score[i * 32 + c] = sim1[pair] + s;
    else sim1[pair] = s;
  }
}

// ---------------------------------------------------------------------------
extern "C" void kernel_launch(void* const* d_in, const int* in_sizes, int n_in,
                              void* d_out, int out_size, void* d_ws, size_t ws_size,
                              hipStream_t stream) {
  const float* img = (const float*)d_in[0];   // [32][36][1024] fp32
  const float* cap = (const float*)d_in[1];   // [32][40][1024] fp32
  const float* Wl  = (const float*)d_in[2];   // [2048][1024] fp32
  const float* bl  = (const float*)d_in[3];   // [1024] fp32
  const float* Wg  = (const float*)d_in[4];
  const float* bg  = (const float*)d_in[5];
  float* out = (float*)d_out;                 // [32][32] fp32

  char* ws = (char*)d_ws;
  float* cnrm = (float*)ws;               ws += 5120;
  float* sim1 = (float*)ws;               ws += 4096;
  u16*   WTl  = (u16*)ws;                 ws += (size_t)1024 * 2048 * 2;   // 4.2 MB
  u16*   WTg  = (u16*)ws;                 ws += (size_t)1024 * 2048 * 2;   // 4.2 MB
  u16*   preL = (u16*)ws;                 ws += (size_t)1280 * 1024 * 2;   // 2.6 MB
  u16*   preG = (u16*)ws;                 ws += (size_t)1280 * 1024 * 2;   // 2.6 MB
  u16*   capb = (u16*)ws;                 ws += (size_t)1280 * 1024 * 2;   // 2.6 MB
  u16*   imgb = (u16*)ws;                 ws += (size_t)1152 * 1024 * 2;   // 2.4 MB
  u16*   Ghi  = (u16*)ws;                 ws += (size_t)32 * 48 * 64 * 2;  // 196 KB
  u16*   Glo  = (u16*)ws;                 ws += (size_t)32 * 48 * 64 * 2;  // 196 KB
  u16*   cwFL = (u16*)ws;                 ws += (size_t)32 * 64 * 2 * 64 * 8 * 2;  // 4.2 MB
  u16*   cwFG = (u16*)ws;                 ws += (size_t)32 * 64 * 2 * 64 * 8 * 2;  // 4.2 MB
  float* S1   = (float*)ws;               ws += (size_t)32 * 1280 * 48 * 4;  // 7.9 MB
  float* S2   = (float*)ws;               ws += (size_t)32 * 1280 * 48 * 4;  // 7.9 MB
  u16*   P1   = (u16*)ws;                 ws += (size_t)32 * 1280 * 64 * 2;  // 5.2 MB

  prep_k<<<8896, 256, 0, stream>>>(img, cap, Wl, Wg, imgb, capb, WTl, WTg,
                                   cnrm, cwFL);
  gemms_k<<<976, 256, 0, stream>>>(capb, imgb, WTl, WTg, preL, preG,
                                   cwFL, cwFG, bl, bg, S1, Ghi, Glo);
  score_k<0><<<256, 256, 0, stream>>>(S1, S1, Ghi, Glo, cnrm, P1, sim1, out);
  gates2_k<<<1280, 256, 0, stream>>>(cwFL, cwFG, P1, preL, preG, capb, imgb, S2);
  score_k<1><<<256, 256, 0, stream>>>(S2, S1, Ghi, Glo, cnrm, P1, sim1, out);
}

// Round 9
// 228.847 us; speedup vs baseline: 1.2050x; 1.2050x over previous
//
#include <hip/hip_runtime.h>
#include <stdint.h>

// C=32 captions, I=32 images, T=40 words, R=36 regions, D=1024.
// R20: fix R19's scratch-spill regression. R19's gates2 showed WRITE 142MB /
// FETCH 145MB (kernel writes only 7.9MB S2) = spill traffic: the one-chunk-
// ahead cwF register prefetch added 32 loop-carried VGPRs past the 64-VGPR
// allocation -> per-chunk spill/reload through scratch. Fix: keep R17's
// 2-barrier structure + R19's cwF fragment layout (1KB contiguous operand
// load/wave, 16x fewer segments than R17's cwT), but load cwF IN-CHUNK with
// a few-instruction live range (declared inside the loop, consumed
// immediately). No other changes vs R19.

typedef unsigned short u16;
typedef __attribute__((ext_vector_type(8))) short bf16x8;
typedef __attribute__((ext_vector_type(4))) float f32x4;

#define MFMA_BF16(a, b, c) __builtin_amdgcn_mfma_f32_16x16x32_bf16((a), (b), (c), 0, 0, 0)

__device__ __forceinline__ float bf2f(u16 u) {
  union { unsigned v; float f; } x; x.v = ((unsigned)u) << 16; return x.f;
}
__device__ __forceinline__ u16 f2bf(float f) {  // round-to-nearest-even
  union { float f; unsigned v; } x; x.f = f;
  return (u16)((x.v + 0x7fffu + ((x.v >> 16) & 1u)) >> 16);
}
__device__ __forceinline__ float frcp(float x) { return __builtin_amdgcn_rcpf(x); }
// async 16B global->LDS (DMA; LDS dest = wave-uniform base + lane*16)
__device__ __forceinline__ void gl2lds16(const u16* g, u16* l) {
  __builtin_amdgcn_global_load_lds((const __attribute__((address_space(1))) void*)g,
                                   (__attribute__((address_space(3))) void*)l, 16, 0, 0);
}

// ---------------------------------------------------------------------------
// prep: [0,2432) fp32->bf16 cvt; [2432,6528) W transpose; [6528,6848) capnorm;
// [6848,8896) zero cwF region (pads; gemms fills r<36 slots afterwards).
__global__ void prep_k(const float* __restrict__ img, const float* __restrict__ cap,
                       const float* __restrict__ Wl, const float* __restrict__ Wg,
                       u16* __restrict__ imgb, u16* __restrict__ capb,
                       u16* __restrict__ WTl, u16* __restrict__ WTg,
                       float* __restrict__ cnorm, u16* __restrict__ cwF0) {
  __shared__ u16 tile[32][33];
  const int b = blockIdx.x, tid = threadIdx.x;
  if (b < 2432) {
    const float* src; u16* dst; int idx;
    if (b < 1152) { src = img; dst = imgb; idx = (b * 256 + tid) * 4; }
    else { src = cap; dst = capb; idx = ((b - 1152) * 256 + tid) * 4; }
    const float4 v = *(const float4*)(src + idx);
    u16 o[4] = {f2bf(v.x), f2bf(v.y), f2bf(v.z), f2bf(v.w)};
    *(uint2*)(dst + idx) = *(const uint2*)o;
  } else if (b < 6528) {
    const int b2 = b - 2432;
    const int bx = b2 & 63, by = (b2 >> 6) & 31, bz = b2 >> 11;
    const float* src = bz ? Wg : Wl;
    u16* dst = bz ? WTg : WTl;
    const int k0 = bx * 32, n0 = by * 32;
    const int tx = tid & 31, ty = tid >> 5;
#pragma unroll
    for (int j = 0; j < 4; ++j)
      tile[ty + 8 * j][tx] = f2bf(src[(size_t)(k0 + ty + 8 * j) * 1024 + n0 + tx]);
    __syncthreads();
#pragma unroll
    for (int j = 0; j < 4; ++j)
      dst[(size_t)(n0 + ty + 8 * j) * 2048 + k0 + tx] = tile[tx][ty + 8 * j];
  } else if (b < 6848) {
    const int wv = tid >> 6, lane = tid & 63;
    const int row = (b - 6528) * 4 + wv;  // < 1280
    const float* p = cap + ((size_t)row << 10) + lane * 16;
    float s = 0.f;
#pragma unroll
    for (int e = 0; e < 16; ++e) { float v = p[e]; s += v * v; }
#pragma unroll
    for (int off = 32; off > 0; off >>= 1) s += __shfl_down(s, off, 64);
    if (lane == 0) cnorm[row] = sqrtf(s);
  } else {
    const int idx = ((b - 6848) * 256 + tid) * 8;
    uint4 z; z.x = z.y = z.z = z.w = 0u;
    *(uint4*)(cwF0 + idx) = z;
  }
}

// ---------------------------------------------------------------------------
// Merged GEMM launch: [0,640) s1gemm; [640,944) gemmw; [944,976) gram.
// gemmw's img part writes cwF fragment layout:
//   element (i, d, r): db=d>>4, lane=((r&31)>>3)*16+(d&15), ks=r>>5, e=r&7
//   index = ((((i*64+db)*2+ks)*64+lane)*8+e
__global__ __launch_bounds__(256, 2) void gemms_k(
    const u16* __restrict__ capb, const u16* __restrict__ imgb,
    const u16* __restrict__ WTl, const u16* __restrict__ WTg,
    u16* __restrict__ preL, u16* __restrict__ preG,
    u16* __restrict__ cwFL, u16* __restrict__ cwFG,
    const float* __restrict__ bL, const float* __restrict__ bG,
    float* __restrict__ S1, u16* __restrict__ Ghi, u16* __restrict__ Glo) {
  __shared__ __align__(16) char lsU[20480];
  const int bid = blockIdx.x;
  const int tid = threadIdx.x;
  const int wv = tid >> 6, lane = tid & 63;
  const int quad = lane >> 4, l15 = lane & 15;
  const bf16x8 zero8 = {0, 0, 0, 0, 0, 0, 0, 0};

  if (bid < 640) {
    // ---- S1 GEMM: out[i][m][r] = sum_d cap[m,d]*ctx_i[r,d]; m-tile 64.
    u16* lsA = (u16*)lsU;
    u16* lsB = (u16*)(lsU + 4096);
    const int i = bid & 31, m0 = (bid >> 5) * 64;
    const u16* B = imgb + (size_t)i * 36 * 1024;
    f32x4 acc[3];
#pragma unroll
    for (int b = 0; b < 3; ++b) acc[b] = (f32x4){0.f, 0.f, 0.f, 0.f};
    for (int kt = 0; kt < 32; ++kt) {
      if (kt) __syncthreads();
      const int rr = tid >> 2, j = tid & 3;
      const int js = j ^ ((rr >> 2) & 3);
      gl2lds16(capb + (size_t)(m0 + rr) * 1024 + kt * 32 + js * 8,
               lsA + (size_t)(wv * 64) * 8);
      const int rc = rr < 36 ? rr : 35;
      gl2lds16(B + (size_t)rc * 1024 + kt * 32 + js * 8,
               lsB + (size_t)(wv * 64) * 8);
      __syncthreads();
      const int ra = wv * 16 + l15;
      const bf16x8 a2 = *(const bf16x8*)(lsA + ra * 32 + (quad ^ ((ra >> 2) & 3)) * 8);
      bf16x8 b3[3];
#pragma unroll
      for (int nf = 0; nf < 3; ++nf) {
        const int rb = nf * 16 + l15;
        const bf16x8 bv = *(const bf16x8*)(lsB + rb * 32 + (quad ^ ((rb >> 2) & 3)) * 8);
        b3[nf] = (rb < 36) ? bv : zero8;
      }
#pragma unroll
      for (int nf = 0; nf < 3; ++nf) acc[nf] = MFMA_BF16(a2, b3[nf], acc[nf]);
    }
#pragma unroll
    for (int nf = 0; nf < 3; ++nf)
#pragma unroll
      for (int rg = 0; rg < 4; ++rg) {
        const int m = m0 + wv * 16 + quad * 4 + rg;
        S1[((size_t)i * 1280 + m) * 48 + nf * 16 + l15] = acc[nf][rg];
      }
  } else if (bid < 944) {
    // ---- dual-B GEMM over A = [capb(1280); imgb(1152)], K=1024.
    u16* lsA = (u16*)lsU;
    u16* lsBl = (u16*)(lsU + 4096);
    u16* lsBg = (u16*)(lsU + 12288);
    const int b2 = bid - 640;
    const int bm = b2 >> 3, bn = b2 & 7;
    const bool iscap = bm < 20;
    const u16* A = iscap ? capb + (size_t)bm * 64 * 1024
                         : imgb + (size_t)(bm - 20) * 64 * 1024;
    const int kofs = iscap ? 0 : 1024;
    const int wm = (wv & 1) * 32, wn = (wv >> 1) * 64;
    f32x4 accL[2][4], accG[2][4];
#pragma unroll
    for (int a = 0; a < 2; ++a)
#pragma unroll
      for (int b = 0; b < 4; ++b) {
        accL[a][b] = (f32x4){0.f, 0.f, 0.f, 0.f};
        accG[a][b] = (f32x4){0.f, 0.f, 0.f, 0.f};
      }
    for (int kt = 0; kt < 32; ++kt) {
      if (kt) __syncthreads();
      {
        const int row = tid >> 2, c8 = tid & 3;
        const int js = c8 ^ (row & 3);
        gl2lds16(A + (size_t)row * 1024 + kt * 32 + js * 8,
                 lsA + (size_t)(wv * 64) * 8);
      }
#pragma unroll
      for (int s = 0; s < 2; ++s) {
        const int idx = s * 256 + tid;
        const int row = idx >> 2, c8 = idx & 3;
        const int js = c8 ^ (row & 3);
        const size_t bro = (size_t)(bn * 128 + row) * 2048 + kofs + kt * 32 + js * 8;
        gl2lds16(WTl + bro, lsBl + (size_t)(s * 256 + wv * 64) * 8);
        gl2lds16(WTg + bro, lsBg + (size_t)(s * 256 + wv * 64) * 8);
      }
      __syncthreads();
      bf16x8 af[2], bl8[4], bg8[4];
#pragma unroll
      for (int mt = 0; mt < 2; ++mt) {
        const int ra = wm + mt * 16 + l15;
        af[mt] = *(const bf16x8*)(lsA + ra * 32 + (quad ^ (ra & 3)) * 8);
      }
#pragma unroll
      for (int nt = 0; nt < 4; ++nt) {
        const int rb = wn + nt * 16 + l15;
        const int off = rb * 32 + (quad ^ (rb & 3)) * 8;
        bl8[nt] = *(const bf16x8*)(lsBl + off);
        bg8[nt] = *(const bf16x8*)(lsBg + off);
      }
#pragma unroll
      for (int mt = 0; mt < 2; ++mt)
#pragma unroll
        for (int nt = 0; nt < 4; ++nt) {
          accL[mt][nt] = MFMA_BF16(af[mt], bl8[nt], accL[mt][nt]);
          accG[mt][nt] = MFMA_BF16(af[mt], bg8[nt], accG[mt][nt]);
        }
    }
#pragma unroll
    for (int mt = 0; mt < 2; ++mt)
#pragma unroll
      for (int nt = 0; nt < 4; ++nt) {
        const int n = bn * 128 + wn + nt * 16 + l15;
        if (iscap) {
          const float blv = bL[n], bgv = bG[n];
#pragma unroll
          for (int r = 0; r < 4; ++r) {
            const int m = bm * 64 + wm + mt * 16 + quad * 4 + r;
            preL[((size_t)m << 10) + n] = f2bf(accL[mt][nt][r] + blv);
            preG[((size_t)m << 10) + n] = f2bf(accG[mt][nt][r] + bgv);
          }
        } else {
          const int db = n >> 4, l15d = n & 15;
#pragma unroll
          for (int r = 0; r < 4; ++r) {
            const int mi = (bm - 20) * 64 + wm + mt * 16 + quad * 4 + r;
            const int i = (mi * 3641) >> 17;   // floor(mi/36), mi<1152
            const int r36 = mi - i * 36;
            const int ksr = r36 >> 5, qd = (r36 & 31) >> 3, e = r36 & 7;
            const size_t gb =
                ((((size_t)i * 64 + db) * 2 + ksr) * 64 + qd * 16 + l15d) * 8 + e;
            cwFL[gb] = f2bf(accL[mt][nt][r]);
            cwFG[gb] = f2bf(accG[mt][nt][r]);
          }
        }
      }
  } else {
    // ---- per-image Gram: G[i] = ctx_i @ ctx_i^T, [48][64] bf16 hi+lo.
    float* lsS = (float*)lsU;  // 48*52*4 = 9984B
    const int i = bid - 944;
    for (int k = tid; k < 48 * 52; k += 256) lsS[k] = 0.f;
    const u16* arow[3]; bool avalid[3];
#pragma unroll
    for (int mt = 0; mt < 3; ++mt) {
      const int r = mt * 16 + l15;
      avalid[mt] = r < 36;
      arow[mt] = imgb + ((size_t)(i * 36 + (r < 36 ? r : 35)) << 10);
    }
    f32x4 acc[3][3];
#pragma unroll
    for (int a = 0; a < 3; ++a)
#pragma unroll
      for (int b = 0; b < 3; ++b) acc[a][b] = (f32x4){0.f, 0.f, 0.f, 0.f};
    for (int kk = wv * 8; kk < wv * 8 + 8; ++kk) {
      const int ko = kk * 32 + quad * 8;
      bf16x8 af[3];
#pragma unroll
      for (int mt = 0; mt < 3; ++mt)
        af[mt] = avalid[mt] ? *(const bf16x8*)(arow[mt] + ko) : zero8;
#pragma unroll
      for (int mt = 0; mt < 3; ++mt)
#pragma unroll
        for (int nt = 0; nt < 3; ++nt)
          acc[mt][nt] = MFMA_BF16(af[mt], af[nt], acc[mt][nt]);
    }
    __syncthreads();
#pragma unroll
    for (int mt = 0; mt < 3; ++mt)
#pragma unroll
      for (int nt = 0; nt < 3; ++nt)
#pragma unroll
        for (int rg = 0; rg < 4; ++rg)
          atomicAdd(&lsS[(nt * 16 + l15) * 52 + mt * 16 + quad * 4 + rg],
                    acc[mt][nt][rg]);
    __syncthreads();
    if (wv == 0) {
#pragma unroll
      for (int nt = 0; nt < 3; ++nt) {
        const int rp = nt * 16 + l15;
#pragma unroll
        for (int mt = 0; mt < 3; ++mt) {
          const f32x4 g = *(const f32x4*)&lsS[rp * 52 + mt * 16 + quad * 4];
          u16 hv[4], lv[4];
#pragma unroll
          for (int rg = 0; rg < 4; ++rg) {
            hv[rg] = f2bf(g[rg]);
            lv[rg] = f2bf(g[rg] - bf2f(hv[rg]));
          }
          const size_t gb = ((size_t)i * 48 + rp) * 64 + mt * 16 + quad * 4;
          *(uint2*)(Ghi + gb) = *(const uint2*)hv;
          *(uint2*)(Glo + gb) = *(const uint2*)lv;
        }
      }
    }
    for (int k = tid; k < 48 * 16; k += 256) {  // zero cols 48..63
      const size_t gb = ((size_t)i * 48 + (k >> 4)) * 64 + 48 + (k & 15);
      Ghi[gb] = 0; Glo[gb] = 0;
    }
  }
}

// ---------------------------------------------------------------------------
// Fused gate + S2 (R17 structure: 32-ct tile, 2 barriers/chunk, grid 1280).
// cwF fragment loads = single contiguous 1KB/wave, loaded IN-CHUNK with a
// short live range (no loop-carried prefetch registers -> no spills).
__global__ __launch_bounds__(256, 4) void gates2_k(
    const u16* __restrict__ cwFL, const u16* __restrict__ cwFG,
    const u16* __restrict__ P1, const u16* __restrict__ preL,
    const u16* __restrict__ preG, const u16* __restrict__ capb,
    const u16* __restrict__ imgb, float* __restrict__ S2) {
  __shared__ __align__(16) u16 lsPre[3][32 * 128];  // [buf][ct][128d] swz
  __shared__ __align__(16) float lsS2f[32 * 52];
  const int tid = threadIdx.x;
  const int bid = blockIdx.x;
  const int i = bid & 31, ctt = bid >> 5;  // i fastest: image i -> XCD i%8
  const int ct0 = ctt * 32;
  const int wv = tid >> 6, lane = tid & 63;
  const int quad = lane >> 4, l15 = lane & 15;

  for (int k = tid; k < 32 * 52; k += 256) lsS2f[k] = 0.f;

  // hoisted P1 B-frags (loop-invariant; r>=36 exact zero from score_k)
  bf16x8 bp[2][2];
#pragma unroll
  for (int nt = 0; nt < 2; ++nt)
#pragma unroll
    for (int ks = 0; ks < 2; ++ks)
      bp[nt][ks] = *(const bf16x8*)(
          P1 + ((size_t)i * 1280 + ct0 + nt * 16 + l15) * 64 + ks * 32 + quad * 8);

  const u16* arow[3]; bool avalid[3];
#pragma unroll
  for (int mt = 0; mt < 3; ++mt) {
    const int r = mt * 16 + l15;
    avalid[mt] = r < 36;
    arow[mt] = imgb + ((size_t)(i * 36 + (r < 36 ? r : 35)) << 10);
  }
  const bf16x8 zero8 = {0, 0, 0, 0, 0, 0, 0, 0};

  f32x4 acc2[3][2];
#pragma unroll
  for (int a = 0; a < 3; ++a)
#pragma unroll
    for (int b = 0; b < 2; ++b) acc2[a][b] = (f32x4){0.f, 0.f, 0.f, 0.f};

#define STAGE(dcx)                                                          \
  {                                                                         \
    _Pragma("unroll")                                                       \
    for (int s = 0; s < 2; ++s) {                                           \
      const int idx = s * 256 + tid;                                        \
      const int rr = idx >> 4, j = idx & 15;                                \
      const int js = j ^ (rr & 7);                                          \
      const size_t src = (size_t)(ct0 + rr) * 1024 + (dcx) * 128 + js * 8;  \
      const size_t dst = (size_t)(s * 256 + wv * 64) * 8;                   \
      gl2lds16(preL + src, lsPre[0] + dst);                                 \
      gl2lds16(preG + src, lsPre[1] + dst);                                 \
      gl2lds16(capb + src, lsPre[2] + dst);                                 \
    }                                                                       \
  }

  STAGE(0);
  for (int dc = 0; dc < 8; ++dc) {
    __syncthreads();  // staging drained; prev epilogue reads fenced

    // ---- gate GEMM: cwF frags loaded in-chunk (1KB contiguous per wave,
    //      consumed immediately -> minimal live range, no spills)
    f32x4 accL[2][2], accG[2][2];
#pragma unroll
    for (int a = 0; a < 2; ++a)
#pragma unroll
      for (int b = 0; b < 2; ++b) {
        accL[a][b] = (f32x4){0.f, 0.f, 0.f, 0.f};
        accG[a][b] = (f32x4){0.f, 0.f, 0.f, 0.f};
      }
#pragma unroll
    for (int mt = 0; mt < 2; ++mt)
#pragma unroll
      for (int ks = 0; ks < 2; ++ks) {
        const int db = dc * 8 + wv * 2 + mt;
        const size_t co = ((((size_t)i * 64 + db) * 2 + ks) * 64 + lane) * 8;
        const bf16x8 al = *(const bf16x8*)(cwFL + co);
        const bf16x8 ag = *(const bf16x8*)(cwFG + co);
#pragma unroll
        for (int nt = 0; nt < 2; ++nt) {
          accL[mt][nt] = MFMA_BF16(al, bp[nt][ks], accL[mt][nt]);
          accG[mt][nt] = MFMA_BF16(ag, bp[nt][ks], accG[mt][nt]);
        }
      }

    // ---- gating epilogue (staged-LDS reads only)
    uint2 ovv[2][2];
#pragma unroll
    for (int mt = 0; mt < 2; ++mt) {
      const int drel = wv * 32 + mt * 16 + quad * 4;
      const int j = drel >> 3;
#pragma unroll
      for (int nt = 0; nt < 2; ++nt) {
        const int rr = nt * 16 + l15;
        const int off = rr * 128 + (j ^ (rr & 7)) * 8 + (quad & 1) * 4;
        const uint2 plv = *(const uint2*)(lsPre[0] + off);
        const uint2 pgv = *(const uint2*)(lsPre[1] + off);
        const uint2 cfv = *(const uint2*)(lsPre[2] + off);
        const float pl4[4] = {bf2f((u16)(plv.x & 0xffffu)), bf2f((u16)(plv.x >> 16)),
                              bf2f((u16)(plv.y & 0xffffu)), bf2f((u16)(plv.y >> 16))};
        const float pg4[4] = {bf2f((u16)(pgv.x & 0xffffu)), bf2f((u16)(pgv.x >> 16)),
                              bf2f((u16)(pgv.y & 0xffffu)), bf2f((u16)(pgv.y >> 16))};
        const float cf4[4] = {bf2f((u16)(cfv.x & 0xffffu)), bf2f((u16)(cfv.x >> 16)),
                              bf2f((u16)(cfv.y & 0xffffu)), bf2f((u16)(cfv.y >> 16))};
        u16 ov[4];
#pragma unroll
        for (int rg = 0; rg < 4; ++rg) {
          const float aL = accL[mt][nt][rg] + pl4[rg];
          const float aG = accG[mt][nt][rg] + pg4[rg];
          const float g = frcp(1.f + __expf(-aG));
          const float u = 2.f * frcp(1.f + __expf(-2.f * aL)) - 1.f;  // tanh
          ov[rg] = f2bf(cf4[rg] * g + u * (1.f - g));
        }
        ovv[mt][nt] = *(const uint2*)ov;
      }
    }
    __syncthreads();  // all lsPre reads done -> next DMA safe
    if (dc < 7) STAGE(dc + 1);  // prefetch under S2 compute

    // ---- S2 partial: B-frag via quad-permute shuffles; wave's 32-d slice
#pragma unroll
    for (int nt = 0; nt < 2; ++nt) {
      unsigned w[4];
#pragma unroll
      for (int j2 = 0; j2 < 4; ++j2) {
        const int srcl = ((quad & 1) * 2 + (j2 >> 1)) * 16 + l15;
        const unsigned a0 =
            __shfl((j2 & 1) ? ovv[0][nt].y : ovv[0][nt].x, srcl, 64);
        const unsigned a1 =
            __shfl((j2 & 1) ? ovv[1][nt].y : ovv[1][nt].x, srcl, 64);
        w[j2] = (quad >= 2) ? a1 : a0;
      }
      union { unsigned u[4]; bf16x8 v; } bq;
      bq.u[0] = w[0]; bq.u[1] = w[1]; bq.u[2] = w[2]; bq.u[3] = w[3];
      const int dg = dc * 128 + wv * 32 + quad * 8;
#pragma unroll
      for (int mt = 0; mt < 3; ++mt) {
        const bf16x8 af = avalid[mt] ? *(const bf16x8*)(arow[mt] + dg) : zero8;
        acc2[mt][nt] = MFMA_BF16(af, bq.v, acc2[mt][nt]);
      }
    }
  }
#undef STAGE
  // ---- merge wave partials (d-slices), write S2 tile
#pragma unroll
  for (int mt = 0; mt < 3; ++mt)
#pragma unroll
    for (int nt = 0; nt < 2; ++nt)
#pragma unroll
      for (int rg = 0; rg < 4; ++rg)
        atomicAdd(&lsS2f[(nt * 16 + l15) * 52 + mt * 16 + quad * 4 + rg],
                  acc2[mt][nt][rg]);
  __syncthreads();
  for (int idx = tid; idx < 384; idx += 256) {
    const int ct = idx / 12, rq = idx % 12;
    *(f32x4*)(S2 + ((size_t)i * 1280 + ct0 + ct) * 48 + rq * 4) =
        *(const f32x4*)&lsS2f[ct * 52 + rq * 4];
  }
}

// ---------------------------------------------------------------------------
// Per-pair scoring (4 pairs/block, one per wave). Softmax(Ssm) -> P;
// pn = sum P*S1; pw = P^T G P; sim = mean cosine. PASS2=0 also writes P1+sim1;
// PASS2=1 writes score = sim1 + sim2.
template <int PASS2>
__global__ __launch_bounds__(256, 2) void score_k(
    const float* __restrict__ Ssm, const float* __restrict__ S1,
    const u16* __restrict__ Ghi, const u16* __restrict__ Glo,
    const float* __restrict__ cnorm, u16* __restrict__ P1,
    float* __restrict__ sim1, float* __restrict__ score) {
  __shared__ __align__(16) u16 lsP[4][48 * 72];
  const int tid = threadIdx.x;
  const int wv = tid >> 6, lane = tid & 63;
  const int quad = lane >> 4, l15 = lane & 15;
  const int pair = blockIdx.x * 4 + wv;
  const int c = pair >> 5, i = pair & 31;
  u16* lsPw = lsP[wv];
  for (int k = lane; k < 1728; k += 64) ((unsigned*)lsPw)[k] = 0u;

  float sS[3][3][4], s1f[3][3][4];
  const float* Sb = Ssm + ((size_t)i * 1280 + c * 40) * 48;
  const float* S1b = S1 + ((size_t)i * 1280 + c * 40) * 48;
#pragma unroll
  for (int nt = 0; nt < 3; ++nt) {
    const int t = nt * 16 + l15;
    const int tr = t < 40 ? t : 39;
#pragma unroll
    for (int mt = 0; mt < 3; ++mt) {
      f32x4 v = *(const f32x4*)(Sb + (size_t)tr * 48 + mt * 16 + quad * 4);
      if (t >= 40) v = (f32x4){0.f, 0.f, 0.f, 0.f};  // keep l2norm-over-t exact
#pragma unroll
      for (int rg = 0; rg < 4; ++rg) sS[mt][nt][rg] = v[rg];
      if (PASS2) {
        const f32x4 w = *(const f32x4*)(S1b + (size_t)tr * 48 + mt * 16 + quad * 4);
#pragma unroll
        for (int rg = 0; rg < 4; ++rg) s1f[mt][nt][rg] = w[rg];
      } else {
#pragma unroll
        for (int rg = 0; rg < 4; ++rg) s1f[mt][nt][rg] = v[rg];
      }
    }
  }

  // ---- leaky + l2norm over t, temperature softmax over r (in-register)
  float rn[3][4];
#pragma unroll
  for (int mt = 0; mt < 3; ++mt)
#pragma unroll
    for (int rg = 0; rg < 4; ++rg) {
      float s2 = 0.f;
#pragma unroll
      for (int nt = 0; nt < 3; ++nt) {
        float v = sS[mt][nt][rg]; v = v > 0.f ? v : 0.1f * v; s2 += v * v;
      }
      s2 += __shfl_xor(s2, 1, 64); s2 += __shfl_xor(s2, 2, 64);
      s2 += __shfl_xor(s2, 4, 64); s2 += __shfl_xor(s2, 8, 64);
      rn[mt][rg] = sqrtf(s2) + 1e-8f;
    }
  float mx[3] = {-3.0e38f, -3.0e38f, -3.0e38f};
#pragma unroll
  for (int mt = 0; mt < 3; ++mt)
#pragma unroll
    for (int nt = 0; nt < 3; ++nt)
#pragma unroll
      for (int rg = 0; rg < 4; ++rg) {
        const int r = mt * 16 + quad * 4 + rg;
        float v = sS[mt][nt][rg]; v = v > 0.f ? v : 0.1f * v;
        float zz = 9.f * v / rn[mt][rg];
        zz = (r < 36) ? zz : -3.0e38f;
        sS[mt][nt][rg] = zz;
        mx[nt] = fmaxf(mx[nt], zz);
      }
#pragma unroll
  for (int nt = 0; nt < 3; ++nt) {
    mx[nt] = fmaxf(mx[nt], __shfl_xor(mx[nt], 16, 64));
    mx[nt] = fmaxf(mx[nt], __shfl_xor(mx[nt], 32, 64));
  }
  float ss[3] = {0.f, 0.f, 0.f};
#pragma unroll
  for (int mt = 0; mt < 3; ++mt)
#pragma unroll
    for (int nt = 0; nt < 3; ++nt)
#pragma unroll
      for (int rg = 0; rg < 4; ++rg) {
        const float e = __expf(sS[mt][nt][rg] - mx[nt]);
        sS[mt][nt][rg] = e; ss[nt] += e;
      }
#pragma unroll
  for (int nt = 0; nt < 3; ++nt) {
    ss[nt] += __shfl_xor(ss[nt], 16, 64);
    ss[nt] += __shfl_xor(ss[nt], 32, 64);
    ss[nt] = 1.f / ss[nt];
  }
#pragma unroll
  for (int nt = 0; nt < 3; ++nt) {
    const int t = nt * 16 + l15;
#pragma unroll
    for (int mt = 0; mt < 3; ++mt) {
#pragma unroll
      for (int rg = 0; rg < 4; ++rg) sS[mt][nt][rg] *= ss[nt];
      if (t < 40) {
        u16 pv[4];
#pragma unroll
        for (int rg = 0; rg < 4; ++rg) pv[rg] = f2bf(sS[mt][nt][rg]);
        *(uint2*)(lsPw + t * 72 + mt * 16 + quad * 4) = *(const uint2*)pv;
      }
    }
  }

  // ---- pn = sum_r P * S1raw (per t)
  float pnv[3] = {0.f, 0.f, 0.f};
#pragma unroll
  for (int nt = 0; nt < 3; ++nt)
#pragma unroll
    for (int mt = 0; mt < 3; ++mt)
#pragma unroll
      for (int rg = 0; rg < 4; ++rg) pnv[nt] += sS[mt][nt][rg] * s1f[mt][nt][rg];

  // ---- P1 global write (GEMM operand layout, stride 64, zeros beyond r=36)
  if (!PASS2) {
    for (int idx = lane; idx < 320; idx += 64) {
      const int t = idx >> 3, j = idx & 7;
      *(uint4*)(P1 + ((size_t)i * 1280 + c * 40 + t) * 64 + j * 8) =
          *(const uint4*)(lsPw + t * 72 + j * 8);
    }
  }

  // ---- pw = P^T G P via Gram MFMA
  bf16x8 afA[3][2];
#pragma unroll
  for (int mtT = 0; mtT < 3; ++mtT)
#pragma unroll
    for (int ks = 0; ks < 2; ++ks)
      afA[mtT][ks] =
          *(const bf16x8*)(lsPw + (mtT * 16 + l15) * 72 + ks * 32 + quad * 8);
  f32x4 gp[3][3];
#pragma unroll
  for (int a = 0; a < 3; ++a)
#pragma unroll
    for (int b = 0; b < 3; ++b) gp[a][b] = (f32x4){0.f, 0.f, 0.f, 0.f};
#pragma unroll
  for (int ks = 0; ks < 2; ++ks)
#pragma unroll
    for (int mtG = 0; mtG < 3; ++mtG) {
      const size_t gb = ((size_t)i * 48 + mtG * 16 + l15) * 64 + ks * 32 + quad * 8;
      const bf16x8 gh = *(const bf16x8*)(Ghi + gb);
      const bf16x8 gl = *(const bf16x8*)(Glo + gb);
#pragma unroll
      for (int mtT = 0; mtT < 3; ++mtT) {
        gp[mtG][mtT] = MFMA_BF16(gh, afA[mtT][ks], gp[mtG][mtT]);
        gp[mtG][mtT] = MFMA_BF16(gl, afA[mtT][ks], gp[mtG][mtT]);
      }
    }
  float pwv[3] = {0.f, 0.f, 0.f};
#pragma unroll
  for (int nt = 0; nt < 3; ++nt)
#pragma unroll
    for (int mt = 0; mt < 3; ++mt)
#pragma unroll
      for (int rg = 0; rg < 4; ++rg)
        pwv[nt] += sS[mt][nt][rg] * gp[mt][nt][rg];
#pragma unroll
  for (int nt = 0; nt < 3; ++nt) {
    pnv[nt] += __shfl_xor(pnv[nt], 16, 64); pnv[nt] += __shfl_xor(pnv[nt], 32, 64);
    pwv[nt] += __shfl_xor(pwv[nt], 16, 64); pwv[nt] += __shfl_xor(pwv[nt], 32, 64);
  }
  float tot = 0.f;
#pragma unroll
  for (int nt = 0; nt < 3; ++nt) {
    const int t = nt * 16 + l15;
    if (t < 40) {
      const float w2 = sqrtf(fmaxf(pwv[nt], 0.f));
      tot += pnv[nt] / fmaxf(cnorm[c * 40 + t] * w2, 1e-8f);
    }
  }
  tot += __shfl_xor(tot, 1, 64); tot += __shfl_xor(tot, 2, 64);
  tot += __shfl_xor(tot, 4, 64); tot += __shfl_xor(tot, 8, 64);
  if (lane == 0) {
    const float s = tot * (1.f / 40.f);
    if (PASS2) score[i * 32 + c] = sim1[pair] + s;
    else sim1[pair] = s;
  }
}

// ---------------------------------------------------------------------------
extern "C" void kernel_launch(void* const* d_in, const int* in_sizes, int n_in,
                              void* d_out, int out_size, void* d_ws, size_t ws_size,
                              hipStream_t stream) {
  const float* img = (const float*)d_in[0];   // [32][36][1024] fp32
  const float* cap = (const float*)d_in[1];   // [32][40][1024] fp32
  const float* Wl  = (const float*)d_in[2];   // [2048][1024] fp32
  const float* bl  = (const float*)d_in[3];   // [1024] fp32
  const float* Wg  = (const float*)d_in[4];
  const float* bg  = (const float*)d_in[5];
  float* out = (float*)d_out;                 // [32][32] fp32

  char* ws = (char*)d_ws;
  float* cnrm = (float*)ws;               ws += 5120;
  float* sim1 = (float*)ws;               ws += 4096;
  u16*   WTl  = (u16*)ws;                 ws += (size_t)1024 * 2048 * 2;   // 4.2 MB
  u16*   WTg  = (u16*)ws;                 ws += (size_t)1024 * 2048 * 2;   // 4.2 MB
  u16*   preL = (u16*)ws;                 ws += (size_t)1280 * 1024 * 2;   // 2.6 MB
  u16*   preG = (u16*)ws;                 ws += (size_t)1280 * 1024 * 2;   // 2.6 MB
  u16*   capb = (u16*)ws;                 ws += (size_t)1280 * 1024 * 2;   // 2.6 MB
  u16*   imgb = (u16*)ws;                 ws += (size_t)1152 * 1024 * 2;   // 2.4 MB
  u16*   Ghi  = (u16*)ws;                 ws += (size_t)32 * 48 * 64 * 2;  // 196 KB
  u16*   Glo  = (u16*)ws;                 ws += (size_t)32 * 48 * 64 * 2;  // 196 KB
  u16*   cwFL = (u16*)ws;                 ws += (size_t)32 * 64 * 2 * 64 * 8 * 2;  // 4.2 MB
  u16*   cwFG = (u16*)ws;                 ws += (size_t)32 * 64 * 2 * 64 * 8 * 2;  // 4.2 MB
  float* S1   = (float*)ws;               ws += (size_t)32 * 1280 * 48 * 4;  // 7.9 MB
  float* S2   = (float*)ws;               ws += (size_t)32 * 1280 * 48 * 4;  // 7.9 MB
  u16*   P1   = (u16*)ws;                 ws += (size_t)32 * 1280 * 64 * 2;  // 5.2 MB

  prep_k<<<8896, 256, 0, stream>>>(img, cap, Wl, Wg, imgb, capb, WTl, WTg,
                                   cnrm, cwFL);
  gemms_k<<<976, 256, 0, stream>>>(capb, imgb, WTl, WTg, preL, preG,
                                   cwFL, cwFG, bl, bg, S1, Ghi, Glo);
  score_k<0><<<256, 256, 0, stream>>>(S1, S1, Ghi, Glo, cnrm, P1, sim1, out);
  gates2_k<<<1280, 256, 0, stream>>>(cwFL, cwFG, P1, preL, preG, capb, imgb, S2);
  score_k<1><<<256, 256, 0, stream>>>(S2, S1, Ghi, Glo, cnrm, P1, sim1, out);
}